// Round 8
// baseline (93.794 us; speedup 1.0000x reference)
//
#include <hip/hip_runtime.h>

// Batched Kalman filter, fully reduced:
//   B    = H @ phi                  (8x16)   Cphi = C @ phi       (8x16)
//   Sc   = H diag(Q) H^T + diag(R)  (8x8)    CQH  = C diag(Q) H^T (8x8)
//   T    = P0 @ B^T                 (16x8 per element)
//   S    = B @ T + Sc               (8x8 SPD, min-eig >= R = 0.1)
//   y    = z - B @ x0
//   w    = S^-1 y                   (redundant per-lane Cholesky, in-register)
//   out  = Cphi @ (x0 + T w) + CQH @ w
// 8 threads per element (thread i owns rows i, i+8), 32 elements per
// 256-thread block. ONE barrier (constants). All cross-lane transport is
// intra-wave LDS b128 round-trips (ds-ordered, barrier-free); group-of-8
// same-address reads broadcast (cheap).
//
// Hard-won structure notes:
//  - plain __launch_bounds__(256): a min-waves hint forced VGPR=40 and
//    ~470 MB of scratch spill traffic in round 2. Never again.
//  - Cross-lane matrix transport via LDS b128; per-scalar shuffles were ~4x
//    DS-pipe issue and +22 us (round 4).
//  - In-register redundant Cholesky beats lane-cooperative GE by 12 us
//    (round 7): no dependent shuffle chain, no divergence, rsq not div.
//  - Round 8: VGPR diet for occupancy — w aliases yf (in-place back-solve),
//    t1 re-read from LDS after solve (its rows 8-15 home survives the S
//    overwrite of rows 0-7; t0 kept in regs). nt loads/stores for streams.

#define QFMA(ACC, OFF, A, V) { ACC[(OFF)+0] += (A)*(V).x; ACC[(OFF)+1] += (A)*(V).y; ACC[(OFF)+2] += (A)*(V).z; ACC[(OFF)+3] += (A)*(V).w; }
#define TS 132  // Tb element stride (words): 132 % 32 == 4 -> groups hit distinct banks
#define XS 28   // x0S element stride (words): 28 % 32 == 28 -> distinct group banks
#define TRI(a,k) ((a)*((a)+1)/2 + (k))

typedef float f4 __attribute__((ext_vector_type(4)));

__global__ __launch_bounds__(256) void kalman_fused8(
    const float* __restrict__ z,
    const float* __restrict__ x0,
    const float* __restrict__ P0,
    const float* __restrict__ phi,
    const float* __restrict__ Hm,
    const float* __restrict__ Cm,
    const float* __restrict__ Qd,
    const float* __restrict__ Rd,
    float* __restrict__ out,
    int bs)
{
    __shared__ __align__(16) float BnS[8 * 20];   // B rows, stride 20
    __shared__ __align__(16) float BTS[16 * 8];   // BTS[k*8+m] = B[m][k] (broadcast reads)
    __shared__ __align__(16) float CpS[8 * 20];   // Cphi rows, stride 20
    __shared__ __align__(16) float CQHS[8 * 8];   // CQH rows
    __shared__ __align__(16) float ScS[8 * 8];    // Sc rows
    __shared__ __align__(16) float x0S[32 * XS];  // words 0..15: x0 (later u); 16..23: y
    __shared__ __align__(16) float Tb[32 * TS];   // words 0..127: T rows (rows 0..7 later reused for S)

    const int tid = threadIdx.x;
    const int e = tid >> 3;   // element in block (0..31)
    const int i = tid & 7;    // lane in element (0..7)
    long b = (long)blockIdx.x * 32 + e;
    const bool valid = (b < (long)bs);
    if (!valid) b = (long)bs - 1;

    // ---- per-element global loads issued first (nt: pure streaming) ----
    f4 Pq[8];
    {
        const f4* P0v = reinterpret_cast<const f4*>(P0 + (size_t)b * 256);
#pragma unroll
        for (int q = 0; q < 4; ++q) {
            Pq[q]     = __builtin_nontemporal_load(&P0v[i * 4 + q]);
            Pq[q + 4] = __builtin_nontemporal_load(&P0v[(i + 8) * 4 + q]);
        }
    }
    const float x0a = __builtin_nontemporal_load(&x0[b * 16 + i]);
    const float x0b = __builtin_nontemporal_load(&x0[b * 16 + 8 + i]);
    float yv = __builtin_nontemporal_load(&z[b * 8 + i]);
    x0S[e * XS + i]     = x0a;
    x0S[e * XS + i + 8] = x0b;

    // ---- derive per-block constants straight from global (tiny, cache-hot) ----
    if (tid < 128) {
        const int m = tid >> 4, k = tid & 15;
        float bv = 0.f, cv = 0.f;
#pragma unroll
        for (int j = 0; j < 16; ++j) {
            const float pj = phi[j * 16 + k];
            bv += Hm[m * 16 + j] * pj;
            cv += Cm[m * 16 + j] * pj;
        }
        BnS[m * 20 + k] = bv;
        BTS[k * 8 + m]  = bv;
        CpS[m * 20 + k] = cv;
    }
    if (tid < 64) {
        const int i2 = tid >> 3, j2 = tid & 7;
        float sc = (i2 == j2) ? Rd[i2] : 0.f;
        float cq = 0.f;
#pragma unroll
        for (int k = 0; k < 16; ++k) {
            const float qh = Qd[k] * Hm[j2 * 16 + k];
            sc += Hm[i2 * 16 + k] * qh;
            cq += Cm[i2 * 16 + k] * qh;
        }
        ScS[i2 * 8 + j2]  = sc;
        CQHS[i2 * 8 + j2] = cq;
    }
    __syncthreads();  // the ONLY barrier

    // ---- T rows i, i+8: T[r][m] = sum_k P0[r][k] * B[m][k] ----
    float t0[8], t1[8];
#pragma unroll
    for (int m = 0; m < 8; ++m) { t0[m] = 0.f; t1[m] = 0.f; }
#pragma unroll
    for (int q = 0; q < 4; ++q) {
        const f4 A = Pq[q], B4 = Pq[q + 4];
        const float a[4] = {A.x, A.y, A.z, A.w};
        const float c[4] = {B4.x, B4.y, B4.z, B4.w};
#pragma unroll
        for (int kk = 0; kk < 4; ++kk) {
            const int k = 4 * q + kk;
            const float4 b0v = *reinterpret_cast<const float4*>(&BTS[k * 8 + 0]);
            const float4 b1v = *reinterpret_cast<const float4*>(&BTS[k * 8 + 4]);
            QFMA(t0, 0, a[kk], b0v) QFMA(t0, 4, a[kk], b1v)
            QFMA(t1, 0, c[kk], b0v) QFMA(t1, 4, c[kk], b1v)
        }
    }
    // stage T (intra-wave round-trip; producer==consumer wave, no barrier)
    *reinterpret_cast<float4*>(&Tb[e * TS + i * 8 + 0]) = make_float4(t0[0], t0[1], t0[2], t0[3]);
    *reinterpret_cast<float4*>(&Tb[e * TS + i * 8 + 4]) = make_float4(t0[4], t0[5], t0[6], t0[7]);
    *reinterpret_cast<float4*>(&Tb[e * TS + (i + 8) * 8 + 0]) = make_float4(t1[0], t1[1], t1[2], t1[3]);
    *reinterpret_cast<float4*>(&Tb[e * TS + (i + 8) * 8 + 4]) = make_float4(t1[4], t1[5], t1[6], t1[7]);

    // ---- B row i -> regs ----
    float br[16];
#pragma unroll
    for (int q = 0; q < 4; ++q) {
        const float4 A = *reinterpret_cast<const float4*>(&BnS[i * 20 + 4 * q]);
        br[4*q+0] = A.x; br[4*q+1] = A.y; br[4*q+2] = A.z; br[4*q+3] = A.w;
    }

    // ---- S row i = Sc[i,:] + B[i,:] @ T (broadcast reads of all T rows) ----
    float s[8];
    {
        const float4 c0 = *reinterpret_cast<const float4*>(&ScS[i * 8 + 0]);
        const float4 c1 = *reinterpret_cast<const float4*>(&ScS[i * 8 + 4]);
        s[0]=c0.x; s[1]=c0.y; s[2]=c0.z; s[3]=c0.w; s[4]=c1.x; s[5]=c1.y; s[6]=c1.z; s[7]=c1.w;
    }
#pragma unroll
    for (int j = 0; j < 16; ++j) {
        const float4 ta = *reinterpret_cast<const float4*>(&Tb[e * TS + j * 8 + 0]);
        const float4 tb = *reinterpret_cast<const float4*>(&Tb[e * TS + j * 8 + 4]);
        const float bij = br[j];
        QFMA(s, 0, bij, ta) QFMA(s, 4, bij, tb)
    }

    // ---- y_i = z_i - B[i,:] @ x0 ----
#pragma unroll
    for (int q = 0; q < 4; ++q) {
        const float4 X = *reinterpret_cast<const float4*>(&x0S[e * XS + 4 * q]);
        yv -= br[4*q+0]*X.x + br[4*q+1]*X.y + br[4*q+2]*X.z + br[4*q+3]*X.w;
    }

    // ---- publish S row (over T rows 0-7; T reads above are done, t1's home
    //      in rows 8-15 survives for the post-solve re-read) and y ----
    *reinterpret_cast<float4*>(&Tb[e * TS + i * 8 + 0]) = make_float4(s[0], s[1], s[2], s[3]);
    *reinterpret_cast<float4*>(&Tb[e * TS + i * 8 + 4]) = make_float4(s[4], s[5], s[6], s[7]);
    x0S[e * XS + 16 + i] = yv;

    // ---- read S lower triangle (12 b128 broadcast reads) + full y ----
    float L[36];
#pragma unroll
    for (int a = 0; a < 8; ++a) {
        const float4 q0 = *reinterpret_cast<const float4*>(&Tb[e * TS + a * 8 + 0]);
        L[TRI(a,0)] = q0.x;
        if (a >= 1) L[TRI(a,1)] = q0.y;
        if (a >= 2) L[TRI(a,2)] = q0.z;
        if (a >= 3) L[TRI(a,3)] = q0.w;
        if (a >= 4) {
            const float4 q1 = *reinterpret_cast<const float4*>(&Tb[e * TS + a * 8 + 4]);
            L[TRI(a,4)] = q1.x;
            if (a >= 5) L[TRI(a,5)] = q1.y;
            if (a >= 6) L[TRI(a,6)] = q1.z;
            if (a >= 7) L[TRI(a,7)] = q1.w;
        }
    }
    float yf[8];
    {
        const float4 ya = *reinterpret_cast<const float4*>(&x0S[e * XS + 16]);
        const float4 yb = *reinterpret_cast<const float4*>(&x0S[e * XS + 20]);
        yf[0]=ya.x; yf[1]=ya.y; yf[2]=ya.z; yf[3]=ya.w;
        yf[4]=yb.x; yf[5]=yb.y; yf[6]=yb.z; yf[7]=yb.w;
    }

    // ---- redundant in-register Cholesky (diag slots hold 1/sqrt after step) ----
#pragma unroll
    for (int k = 0; k < 8; ++k) {
        const float inv = __builtin_amdgcn_rsqf(L[TRI(k,k)]);
        L[TRI(k,k)] = inv;
#pragma unroll
        for (int a = k + 1; a < 8; ++a) L[TRI(a,k)] *= inv;
#pragma unroll
        for (int a = k + 1; a < 8; ++a) {
#pragma unroll
            for (int m = k + 1; m <= a; ++m)
                L[TRI(a,m)] -= L[TRI(a,k)] * L[TRI(m,k)];
        }
    }
    // forward solve L y' = y, then back solve L^T w = y' — both IN PLACE (w == yf)
#pragma unroll
    for (int a = 0; a < 8; ++a) {
        float t = yf[a];
#pragma unroll
        for (int j = 0; j < a; ++j) t -= L[TRI(a,j)] * yf[j];
        yf[a] = t * L[TRI(a,a)];
    }
#pragma unroll
    for (int a = 7; a >= 0; --a) {
        float t = yf[a];
#pragma unroll
        for (int j = a + 1; j < 8; ++j) t -= L[TRI(j,a)] * yf[j];
        yf[a] = t * L[TRI(a,a)];
    }
    // yf now holds w

    // ---- u rows = x0 + T w ; t0 from regs, t1 re-read from LDS ----
    float th0 = 0.f, th1 = 0.f;
#pragma unroll
    for (int m = 0; m < 8; ++m) th0 += t0[m] * yf[m];
    {
        const float4 ta = *reinterpret_cast<const float4*>(&Tb[e * TS + (i + 8) * 8 + 0]);
        const float4 tb = *reinterpret_cast<const float4*>(&Tb[e * TS + (i + 8) * 8 + 4]);
        th1 = ta.x*yf[0] + ta.y*yf[1] + ta.z*yf[2] + ta.w*yf[3]
            + tb.x*yf[4] + tb.y*yf[5] + tb.z*yf[6] + tb.w*yf[7];
    }
    x0S[e * XS + i]     = x0a + th0;
    x0S[e * XS + i + 8] = x0b + th1;

    // ---- out[b][i] = Cphi[i,:] @ u + CQH[i,:] @ w ----
    float oc = 0.f;
#pragma unroll
    for (int q = 0; q < 4; ++q) {
        const float4 A = *reinterpret_cast<const float4*>(&CpS[i * 20 + 4 * q]);
        const float4 U = *reinterpret_cast<const float4*>(&x0S[e * XS + 4 * q]);
        oc += A.x*U.x + A.y*U.y + A.z*U.z + A.w*U.w;
    }
    {
        const float4 q0 = *reinterpret_cast<const float4*>(&CQHS[i * 8 + 0]);
        const float4 q1 = *reinterpret_cast<const float4*>(&CQHS[i * 8 + 4]);
        oc += q0.x*yf[0] + q0.y*yf[1] + q0.z*yf[2] + q0.w*yf[3]
            + q1.x*yf[4] + q1.y*yf[5] + q1.z*yf[6] + q1.w*yf[7];
    }
    if (valid) __builtin_nontemporal_store(oc, &out[b * 8 + i]);
}

extern "C" void kernel_launch(void* const* d_in, const int* in_sizes, int n_in,
                              void* d_out, int out_size, void* d_ws, size_t ws_size,
                              hipStream_t stream)
{
    const float* z   = (const float*)d_in[0];
    const float* x0  = (const float*)d_in[1];
    const float* P0  = (const float*)d_in[2];
    const float* phi = (const float*)d_in[3];
    const float* H   = (const float*)d_in[4];
    const float* C   = (const float*)d_in[5];
    const float* Qd  = (const float*)d_in[6];
    const float* Rd  = (const float*)d_in[7];
    float* out = (float*)d_out;

    const int bs = in_sizes[0] / 8;          // z is [bs, 8]
    const int blocks = (bs + 31) / 32;       // 32 elements per block
    hipLaunchKernelGGL(kalman_fused8, dim3(blocks), dim3(256), 0, stream,
                       z, x0, P0, phi, H, C, Qd, Rd, out, bs);
}

// Round 9
// 69.484 us; speedup vs baseline: 1.3499x; 1.3499x over previous
//
#include <hip/hip_runtime.h>

// Batched Kalman filter, fully reduced:
//   B    = H @ phi                  (8x16)   Cphi = C @ phi       (8x16)
//   Sc   = H diag(Q) H^T + diag(R)  (8x8)    CQH  = C diag(Q) H^T (8x8)
//   T    = P0 @ B^T                 (16x8 per element)
//   S    = B @ T + Sc               (8x8 SPD, min-eig >= R = 0.1)
//   y    = z - B @ x0
//   w    = S^-1 y                   (redundant per-lane Cholesky, in-register)
//   out  = Cphi @ (x0 + T w) + CQH @ w
// 8 threads per element (thread i owns rows i, i+8), 32 elements per
// 256-thread block. ONE barrier (constants). All cross-lane transport is
// intra-wave LDS b128 round-trips (ds-ordered, barrier-free); group-of-8
// same-address reads broadcast (cheap).
//
// Hard-won structure notes:
//  - plain __launch_bounds__(256): a min-waves hint forced VGPR=40 and
//    ~470 MB of scratch spill traffic in round 2. Never again.
//  - Cross-lane matrix transport via LDS b128; per-scalar shuffles were ~4x
//    DS-pipe issue and +22 us (round 4).
//  - In-register redundant Cholesky beats lane-cooperative GE by 12 us
//    (round 7): no dependent shuffle chain, no divergence, rsq not div.
//  - NO nontemporal loads: P0's lane-strided 64B row-ownership pattern
//    consumes each cache line across 4 instructions; nt bypassed line reuse
//    -> ~4x P0 HBM traffic, 68->94 us (round 8).
//  - In-place back-substitution (w aliases yf): -8 VGPR at peak, free.

#define QFMA(ACC, OFF, A, V) { ACC[(OFF)+0] += (A)*(V).x; ACC[(OFF)+1] += (A)*(V).y; ACC[(OFF)+2] += (A)*(V).z; ACC[(OFF)+3] += (A)*(V).w; }
#define TS 132  // Tb element stride (words): 132 % 32 == 4 -> groups hit distinct banks
#define XS 28   // x0S element stride (words): 28 % 32 == 28 -> distinct group banks
#define TRI(a,k) ((a)*((a)+1)/2 + (k))

__global__ __launch_bounds__(256) void kalman_fused9(
    const float* __restrict__ z,
    const float* __restrict__ x0,
    const float* __restrict__ P0,
    const float* __restrict__ phi,
    const float* __restrict__ Hm,
    const float* __restrict__ Cm,
    const float* __restrict__ Qd,
    const float* __restrict__ Rd,
    float* __restrict__ out,
    int bs)
{
    __shared__ __align__(16) float BnS[8 * 20];   // B rows, stride 20
    __shared__ __align__(16) float BTS[16 * 8];   // BTS[k*8+m] = B[m][k] (broadcast reads)
    __shared__ __align__(16) float CpS[8 * 20];   // Cphi rows, stride 20
    __shared__ __align__(16) float CQHS[8 * 8];   // CQH rows
    __shared__ __align__(16) float ScS[8 * 8];    // Sc rows
    __shared__ __align__(16) float x0S[32 * XS];  // words 0..15: x0 (later u); 16..23: y
    __shared__ __align__(16) float Tb[32 * TS];   // words 0..127: T rows (rows 0..7 later reused for S)

    const int tid = threadIdx.x;
    const int e = tid >> 3;   // element in block (0..31)
    const int i = tid & 7;    // lane in element (0..7)
    long b = (long)blockIdx.x * 32 + e;
    const bool valid = (b < (long)bs);
    if (!valid) b = (long)bs - 1;

    // ---- per-element global loads issued first (latency hides under derive) ----
    float4 Pq[8];
    {
        const float4* P0v = reinterpret_cast<const float4*>(P0 + (size_t)b * 256);
#pragma unroll
        for (int q = 0; q < 4; ++q) {
            Pq[q]     = P0v[i * 4 + q];
            Pq[q + 4] = P0v[(i + 8) * 4 + q];
        }
    }
    const float x0a = x0[b * 16 + i];
    const float x0b = x0[b * 16 + 8 + i];
    float yv = z[b * 8 + i];
    x0S[e * XS + i]     = x0a;
    x0S[e * XS + i + 8] = x0b;

    // ---- derive per-block constants straight from global (tiny, cache-hot) ----
    if (tid < 128) {
        const int m = tid >> 4, k = tid & 15;
        float bv = 0.f, cv = 0.f;
#pragma unroll
        for (int j = 0; j < 16; ++j) {
            const float pj = phi[j * 16 + k];
            bv += Hm[m * 16 + j] * pj;
            cv += Cm[m * 16 + j] * pj;
        }
        BnS[m * 20 + k] = bv;
        BTS[k * 8 + m]  = bv;
        CpS[m * 20 + k] = cv;
    }
    if (tid < 64) {
        const int i2 = tid >> 3, j2 = tid & 7;
        float sc = (i2 == j2) ? Rd[i2] : 0.f;
        float cq = 0.f;
#pragma unroll
        for (int k = 0; k < 16; ++k) {
            const float qh = Qd[k] * Hm[j2 * 16 + k];
            sc += Hm[i2 * 16 + k] * qh;
            cq += Cm[i2 * 16 + k] * qh;
        }
        ScS[i2 * 8 + j2]  = sc;
        CQHS[i2 * 8 + j2] = cq;
    }
    __syncthreads();  // the ONLY barrier

    // ---- T rows i, i+8: T[r][m] = sum_k P0[r][k] * B[m][k] ----
    float t0[8], t1[8];
#pragma unroll
    for (int m = 0; m < 8; ++m) { t0[m] = 0.f; t1[m] = 0.f; }
#pragma unroll
    for (int q = 0; q < 4; ++q) {
        const float4 A = Pq[q], B4 = Pq[q + 4];
        const float a[4] = {A.x, A.y, A.z, A.w};
        const float c[4] = {B4.x, B4.y, B4.z, B4.w};
#pragma unroll
        for (int kk = 0; kk < 4; ++kk) {
            const int k = 4 * q + kk;
            const float4 b0v = *reinterpret_cast<const float4*>(&BTS[k * 8 + 0]);
            const float4 b1v = *reinterpret_cast<const float4*>(&BTS[k * 8 + 4]);
            QFMA(t0, 0, a[kk], b0v) QFMA(t0, 4, a[kk], b1v)
            QFMA(t1, 0, c[kk], b0v) QFMA(t1, 4, c[kk], b1v)
        }
    }
    // stage T (intra-wave round-trip; producer==consumer wave, no barrier)
    *reinterpret_cast<float4*>(&Tb[e * TS + i * 8 + 0]) = make_float4(t0[0], t0[1], t0[2], t0[3]);
    *reinterpret_cast<float4*>(&Tb[e * TS + i * 8 + 4]) = make_float4(t0[4], t0[5], t0[6], t0[7]);
    *reinterpret_cast<float4*>(&Tb[e * TS + (i + 8) * 8 + 0]) = make_float4(t1[0], t1[1], t1[2], t1[3]);
    *reinterpret_cast<float4*>(&Tb[e * TS + (i + 8) * 8 + 4]) = make_float4(t1[4], t1[5], t1[6], t1[7]);

    // ---- B row i -> regs ----
    float br[16];
#pragma unroll
    for (int q = 0; q < 4; ++q) {
        const float4 A = *reinterpret_cast<const float4*>(&BnS[i * 20 + 4 * q]);
        br[4*q+0] = A.x; br[4*q+1] = A.y; br[4*q+2] = A.z; br[4*q+3] = A.w;
    }

    // ---- S row i = Sc[i,:] + B[i,:] @ T (broadcast reads of all T rows) ----
    float s[8];
    {
        const float4 c0 = *reinterpret_cast<const float4*>(&ScS[i * 8 + 0]);
        const float4 c1 = *reinterpret_cast<const float4*>(&ScS[i * 8 + 4]);
        s[0]=c0.x; s[1]=c0.y; s[2]=c0.z; s[3]=c0.w; s[4]=c1.x; s[5]=c1.y; s[6]=c1.z; s[7]=c1.w;
    }
#pragma unroll
    for (int j = 0; j < 16; ++j) {
        const float4 ta = *reinterpret_cast<const float4*>(&Tb[e * TS + j * 8 + 0]);
        const float4 tb = *reinterpret_cast<const float4*>(&Tb[e * TS + j * 8 + 4]);
        const float bij = br[j];
        QFMA(s, 0, bij, ta) QFMA(s, 4, bij, tb)
    }

    // ---- y_i = z_i - B[i,:] @ x0 ----
#pragma unroll
    for (int q = 0; q < 4; ++q) {
        const float4 X = *reinterpret_cast<const float4*>(&x0S[e * XS + 4 * q]);
        yv -= br[4*q+0]*X.x + br[4*q+1]*X.y + br[4*q+2]*X.z + br[4*q+3]*X.w;
    }

    // ---- publish S row (reuse Tb rows 0-7: all T reads above are done) and y ----
    *reinterpret_cast<float4*>(&Tb[e * TS + i * 8 + 0]) = make_float4(s[0], s[1], s[2], s[3]);
    *reinterpret_cast<float4*>(&Tb[e * TS + i * 8 + 4]) = make_float4(s[4], s[5], s[6], s[7]);
    x0S[e * XS + 16 + i] = yv;

    // ---- read S lower triangle (12 b128 broadcast reads) + full y ----
    float L[36];
#pragma unroll
    for (int a = 0; a < 8; ++a) {
        const float4 q0 = *reinterpret_cast<const float4*>(&Tb[e * TS + a * 8 + 0]);
        L[TRI(a,0)] = q0.x;
        if (a >= 1) L[TRI(a,1)] = q0.y;
        if (a >= 2) L[TRI(a,2)] = q0.z;
        if (a >= 3) L[TRI(a,3)] = q0.w;
        if (a >= 4) {
            const float4 q1 = *reinterpret_cast<const float4*>(&Tb[e * TS + a * 8 + 4]);
            L[TRI(a,4)] = q1.x;
            if (a >= 5) L[TRI(a,5)] = q1.y;
            if (a >= 6) L[TRI(a,6)] = q1.z;
            if (a >= 7) L[TRI(a,7)] = q1.w;
        }
    }
    float yf[8];
    {
        const float4 ya = *reinterpret_cast<const float4*>(&x0S[e * XS + 16]);
        const float4 yb = *reinterpret_cast<const float4*>(&x0S[e * XS + 20]);
        yf[0]=ya.x; yf[1]=ya.y; yf[2]=ya.z; yf[3]=ya.w;
        yf[4]=yb.x; yf[5]=yb.y; yf[6]=yb.z; yf[7]=yb.w;
    }

    // ---- redundant in-register Cholesky (diag slots hold 1/sqrt after step) ----
#pragma unroll
    for (int k = 0; k < 8; ++k) {
        const float inv = __builtin_amdgcn_rsqf(L[TRI(k,k)]);
        L[TRI(k,k)] = inv;
#pragma unroll
        for (int a = k + 1; a < 8; ++a) L[TRI(a,k)] *= inv;
#pragma unroll
        for (int a = k + 1; a < 8; ++a) {
#pragma unroll
            for (int m = k + 1; m <= a; ++m)
                L[TRI(a,m)] -= L[TRI(a,k)] * L[TRI(m,k)];
        }
    }
    // forward solve L y' = y, then back solve L^T w = y' — both IN PLACE (w aliases yf)
#pragma unroll
    for (int a = 0; a < 8; ++a) {
        float t = yf[a];
#pragma unroll
        for (int j = 0; j < a; ++j) t -= L[TRI(a,j)] * yf[j];
        yf[a] = t * L[TRI(a,a)];
    }
#pragma unroll
    for (int a = 7; a >= 0; --a) {
        float t = yf[a];
#pragma unroll
        for (int j = a + 1; j < 8; ++j) t -= L[TRI(j,a)] * yf[j];
        yf[a] = t * L[TRI(a,a)];
    }
    // yf now holds w

    // ---- u rows = x0 + T w (registers), publish u (x0S words 0-15 reusable) ----
    float th0 = 0.f, th1 = 0.f;
#pragma unroll
    for (int m = 0; m < 8; ++m) { th0 += t0[m] * yf[m]; th1 += t1[m] * yf[m]; }
    x0S[e * XS + i]     = x0a + th0;
    x0S[e * XS + i + 8] = x0b + th1;

    // ---- out[b][i] = Cphi[i,:] @ u + CQH[i,:] @ w ----
    float oc = 0.f;
#pragma unroll
    for (int q = 0; q < 4; ++q) {
        const float4 A = *reinterpret_cast<const float4*>(&CpS[i * 20 + 4 * q]);
        const float4 U = *reinterpret_cast<const float4*>(&x0S[e * XS + 4 * q]);
        oc += A.x*U.x + A.y*U.y + A.z*U.z + A.w*U.w;
    }
    {
        const float4 q0 = *reinterpret_cast<const float4*>(&CQHS[i * 8 + 0]);
        const float4 q1 = *reinterpret_cast<const float4*>(&CQHS[i * 8 + 4]);
        oc += q0.x*yf[0] + q0.y*yf[1] + q0.z*yf[2] + q0.w*yf[3]
            + q1.x*yf[4] + q1.y*yf[5] + q1.z*yf[6] + q1.w*yf[7];
    }
    if (valid) out[b * 8 + i] = oc;
}

extern "C" void kernel_launch(void* const* d_in, const int* in_sizes, int n_in,
                              void* d_out, int out_size, void* d_ws, size_t ws_size,
                              hipStream_t stream)
{
    const float* z   = (const float*)d_in[0];
    const float* x0  = (const float*)d_in[1];
    const float* P0  = (const float*)d_in[2];
    const float* phi = (const float*)d_in[3];
    const float* H   = (const float*)d_in[4];
    const float* C   = (const float*)d_in[5];
    const float* Qd  = (const float*)d_in[6];
    const float* Rd  = (const float*)d_in[7];
    float* out = (float*)d_out;

    const int bs = in_sizes[0] / 8;          // z is [bs, 8]
    const int blocks = (bs + 31) / 32;       // 32 elements per block
    hipLaunchKernelGGL(kalman_fused9, dim3(blocks), dim3(256), 0, stream,
                       z, x0, P0, phi, H, C, Qd, Rd, out, bs);
}

// Round 10
// 68.929 us; speedup vs baseline: 1.3607x; 1.0080x over previous
//
#include <hip/hip_runtime.h>

// Batched Kalman filter, fully reduced:
//   B    = H @ phi                  (8x16)   Cphi = C @ phi       (8x16)
//   Sc   = H diag(Q) H^T + diag(R)  (8x8)    CQH  = C diag(Q) H^T (8x8)
//   T    = P0 @ B^T                 (16x8 per element)
//   S    = B @ T + Sc               (8x8 SPD, min-eig >= R = 0.1)
//   y    = z - B @ x0
//   w    = S^-1 y                   (redundant per-lane Cholesky, in-register)
//   out  = Cphi @ (x0 + T w) + CQH @ w
// 8 threads per element (thread i owns rows i, i+8), 32 elements per
// 256-thread block. ONE barrier (constants). All cross-lane transport is
// intra-wave LDS b128 round-trips (ds-ordered, barrier-free); group-of-8
// same-address reads broadcast (cheap).
//
// Hard-won structure notes:
//  - plain __launch_bounds__(256): a min-waves hint forced VGPR=40 and
//    ~470 MB of scratch spill traffic in round 2. Never again.
//  - Cross-lane matrix transport via LDS b128; per-scalar shuffles were ~4x
//    DS-pipe issue and +22 us (round 4).
//  - In-register redundant Cholesky beats lane-cooperative GE by 12 us
//    (round 7): no dependent shuffle chain, no divergence, rsq not div.
//  - NO nontemporal loads: P0's lane-strided 64B row-ownership pattern
//    consumes each cache line across 4 instructions; nt bypassed line reuse
//    -> ~4x P0 HBM traffic, 68->94 us (round 8).
//  - Round 10: VGPR diet for 5 waves/SIMD — S published to its own LDS
//    region (Tb words 128-191; stride 132->196, same bank rotation) so T
//    rows survive; t0/t1 re-read from LDS on the tail. t0/t1 die at the
//    staging point -> ~16 fewer live VGPRs through S-build + Cholesky.

#define QFMA(ACC, OFF, A, V) { ACC[(OFF)+0] += (A)*(V).x; ACC[(OFF)+1] += (A)*(V).y; ACC[(OFF)+2] += (A)*(V).z; ACC[(OFF)+3] += (A)*(V).w; }
#define TS 196   // Tb element stride (words): 196 % 32 == 4 -> element groups rotate banks
#define SOFF 128 // S region offset within a Tb element (words 128..191)
#define XS 28    // x0S element stride (words)
#define TRI(a,k) ((a)*((a)+1)/2 + (k))

__global__ __launch_bounds__(256) void kalman_fused10(
    const float* __restrict__ z,
    const float* __restrict__ x0,
    const float* __restrict__ P0,
    const float* __restrict__ phi,
    const float* __restrict__ Hm,
    const float* __restrict__ Cm,
    const float* __restrict__ Qd,
    const float* __restrict__ Rd,
    float* __restrict__ out,
    int bs)
{
    __shared__ __align__(16) float BnS[8 * 20];   // B rows, stride 20
    __shared__ __align__(16) float BTS[16 * 8];   // BTS[k*8+m] = B[m][k] (broadcast reads)
    __shared__ __align__(16) float CpS[8 * 20];   // Cphi rows, stride 20
    __shared__ __align__(16) float CQHS[8 * 8];   // CQH rows
    __shared__ __align__(16) float ScS[8 * 8];    // Sc rows
    __shared__ __align__(16) float x0S[32 * XS];  // words 0..15: x0 (later u); 16..23: y
    __shared__ __align__(16) float Tb[32 * TS];   // words 0..127: T rows; 128..191: S rows

    const int tid = threadIdx.x;
    const int e = tid >> 3;   // element in block (0..31)
    const int i = tid & 7;    // lane in element (0..7)
    long b = (long)blockIdx.x * 32 + e;
    const bool valid = (b < (long)bs);
    if (!valid) b = (long)bs - 1;

    // ---- per-element global loads issued first (latency hides under derive) ----
    float4 Pq[8];
    {
        const float4* P0v = reinterpret_cast<const float4*>(P0 + (size_t)b * 256);
#pragma unroll
        for (int q = 0; q < 4; ++q) {
            Pq[q]     = P0v[i * 4 + q];
            Pq[q + 4] = P0v[(i + 8) * 4 + q];
        }
    }
    const float x0a = x0[b * 16 + i];
    const float x0b = x0[b * 16 + 8 + i];
    float yv = z[b * 8 + i];
    x0S[e * XS + i]     = x0a;
    x0S[e * XS + i + 8] = x0b;

    // ---- derive per-block constants straight from global (tiny, cache-hot) ----
    if (tid < 128) {
        const int m = tid >> 4, k = tid & 15;
        float bv = 0.f, cv = 0.f;
#pragma unroll
        for (int j = 0; j < 16; ++j) {
            const float pj = phi[j * 16 + k];
            bv += Hm[m * 16 + j] * pj;
            cv += Cm[m * 16 + j] * pj;
        }
        BnS[m * 20 + k] = bv;
        BTS[k * 8 + m]  = bv;
        CpS[m * 20 + k] = cv;
    }
    if (tid < 64) {
        const int i2 = tid >> 3, j2 = tid & 7;
        float sc = (i2 == j2) ? Rd[i2] : 0.f;
        float cq = 0.f;
#pragma unroll
        for (int k = 0; k < 16; ++k) {
            const float qh = Qd[k] * Hm[j2 * 16 + k];
            sc += Hm[i2 * 16 + k] * qh;
            cq += Cm[i2 * 16 + k] * qh;
        }
        ScS[i2 * 8 + j2]  = sc;
        CQHS[i2 * 8 + j2] = cq;
    }
    __syncthreads();  // the ONLY barrier

    // ---- T rows i, i+8: T[r][m] = sum_k P0[r][k] * B[m][k] ----
    {
        float t0[8], t1[8];
#pragma unroll
        for (int m = 0; m < 8; ++m) { t0[m] = 0.f; t1[m] = 0.f; }
#pragma unroll
        for (int q = 0; q < 4; ++q) {
            const float4 A = Pq[q], B4 = Pq[q + 4];
            const float a[4] = {A.x, A.y, A.z, A.w};
            const float c[4] = {B4.x, B4.y, B4.z, B4.w};
#pragma unroll
            for (int kk = 0; kk < 4; ++kk) {
                const int k = 4 * q + kk;
                const float4 b0v = *reinterpret_cast<const float4*>(&BTS[k * 8 + 0]);
                const float4 b1v = *reinterpret_cast<const float4*>(&BTS[k * 8 + 4]);
                QFMA(t0, 0, a[kk], b0v) QFMA(t0, 4, a[kk], b1v)
                QFMA(t1, 0, c[kk], b0v) QFMA(t1, 4, c[kk], b1v)
            }
        }
        // stage T (intra-wave round-trip; producer==consumer wave, no barrier)
        // t0/t1 DIE here -> ~16 fewer live VGPRs through S-build and solve.
        *reinterpret_cast<float4*>(&Tb[e * TS + i * 8 + 0]) = make_float4(t0[0], t0[1], t0[2], t0[3]);
        *reinterpret_cast<float4*>(&Tb[e * TS + i * 8 + 4]) = make_float4(t0[4], t0[5], t0[6], t0[7]);
        *reinterpret_cast<float4*>(&Tb[e * TS + (i + 8) * 8 + 0]) = make_float4(t1[0], t1[1], t1[2], t1[3]);
        *reinterpret_cast<float4*>(&Tb[e * TS + (i + 8) * 8 + 4]) = make_float4(t1[4], t1[5], t1[6], t1[7]);
    }

    // ---- B row i -> regs ----
    float br[16];
#pragma unroll
    for (int q = 0; q < 4; ++q) {
        const float4 A = *reinterpret_cast<const float4*>(&BnS[i * 20 + 4 * q]);
        br[4*q+0] = A.x; br[4*q+1] = A.y; br[4*q+2] = A.z; br[4*q+3] = A.w;
    }

    // ---- S row i = Sc[i,:] + B[i,:] @ T (broadcast reads of all T rows) ----
    float s[8];
    {
        const float4 c0 = *reinterpret_cast<const float4*>(&ScS[i * 8 + 0]);
        const float4 c1 = *reinterpret_cast<const float4*>(&ScS[i * 8 + 4]);
        s[0]=c0.x; s[1]=c0.y; s[2]=c0.z; s[3]=c0.w; s[4]=c1.x; s[5]=c1.y; s[6]=c1.z; s[7]=c1.w;
    }
#pragma unroll
    for (int j = 0; j < 16; ++j) {
        const float4 ta = *reinterpret_cast<const float4*>(&Tb[e * TS + j * 8 + 0]);
        const float4 tb = *reinterpret_cast<const float4*>(&Tb[e * TS + j * 8 + 4]);
        const float bij = br[j];
        QFMA(s, 0, bij, ta) QFMA(s, 4, bij, tb)
    }

    // ---- y_i = z_i - B[i,:] @ x0 ----
#pragma unroll
    for (int q = 0; q < 4; ++q) {
        const float4 X = *reinterpret_cast<const float4*>(&x0S[e * XS + 4 * q]);
        yv -= br[4*q+0]*X.x + br[4*q+1]*X.y + br[4*q+2]*X.z + br[4*q+3]*X.w;
    }

    // ---- publish S row into its own region (T rows stay intact) and y ----
    *reinterpret_cast<float4*>(&Tb[e * TS + SOFF + i * 8 + 0]) = make_float4(s[0], s[1], s[2], s[3]);
    *reinterpret_cast<float4*>(&Tb[e * TS + SOFF + i * 8 + 4]) = make_float4(s[4], s[5], s[6], s[7]);
    x0S[e * XS + 16 + i] = yv;

    // ---- read S lower triangle (12 b128 broadcast reads) + full y ----
    float L[36];
#pragma unroll
    for (int a = 0; a < 8; ++a) {
        const float4 q0 = *reinterpret_cast<const float4*>(&Tb[e * TS + SOFF + a * 8 + 0]);
        L[TRI(a,0)] = q0.x;
        if (a >= 1) L[TRI(a,1)] = q0.y;
        if (a >= 2) L[TRI(a,2)] = q0.z;
        if (a >= 3) L[TRI(a,3)] = q0.w;
        if (a >= 4) {
            const float4 q1 = *reinterpret_cast<const float4*>(&Tb[e * TS + SOFF + a * 8 + 4]);
            L[TRI(a,4)] = q1.x;
            if (a >= 5) L[TRI(a,5)] = q1.y;
            if (a >= 6) L[TRI(a,6)] = q1.z;
            if (a >= 7) L[TRI(a,7)] = q1.w;
        }
    }
    float yf[8];
    {
        const float4 ya = *reinterpret_cast<const float4*>(&x0S[e * XS + 16]);
        const float4 yb = *reinterpret_cast<const float4*>(&x0S[e * XS + 20]);
        yf[0]=ya.x; yf[1]=ya.y; yf[2]=ya.z; yf[3]=ya.w;
        yf[4]=yb.x; yf[5]=yb.y; yf[6]=yb.z; yf[7]=yb.w;
    }

    // ---- redundant in-register Cholesky (diag slots hold 1/sqrt after step) ----
#pragma unroll
    for (int k = 0; k < 8; ++k) {
        const float inv = __builtin_amdgcn_rsqf(L[TRI(k,k)]);
        L[TRI(k,k)] = inv;
#pragma unroll
        for (int a = k + 1; a < 8; ++a) L[TRI(a,k)] *= inv;
#pragma unroll
        for (int a = k + 1; a < 8; ++a) {
#pragma unroll
            for (int m = k + 1; m <= a; ++m)
                L[TRI(a,m)] -= L[TRI(a,k)] * L[TRI(m,k)];
        }
    }
    // forward solve L y' = y, then back solve L^T w = y' — both IN PLACE (w aliases yf)
#pragma unroll
    for (int a = 0; a < 8; ++a) {
        float t = yf[a];
#pragma unroll
        for (int j = 0; j < a; ++j) t -= L[TRI(a,j)] * yf[j];
        yf[a] = t * L[TRI(a,a)];
    }
#pragma unroll
    for (int a = 7; a >= 0; --a) {
        float t = yf[a];
#pragma unroll
        for (int j = a + 1; j < 8; ++j) t -= L[TRI(j,a)] * yf[j];
        yf[a] = t * L[TRI(a,a)];
    }
    // yf now holds w

    // ---- u rows = x0 + T w ; T rows re-read from LDS (intact) ----
    float th0, th1;
    {
        const float4 a0 = *reinterpret_cast<const float4*>(&Tb[e * TS + i * 8 + 0]);
        const float4 a1 = *reinterpret_cast<const float4*>(&Tb[e * TS + i * 8 + 4]);
        th0 = a0.x*yf[0] + a0.y*yf[1] + a0.z*yf[2] + a0.w*yf[3]
            + a1.x*yf[4] + a1.y*yf[5] + a1.z*yf[6] + a1.w*yf[7];
        const float4 b0 = *reinterpret_cast<const float4*>(&Tb[e * TS + (i + 8) * 8 + 0]);
        const float4 b1 = *reinterpret_cast<const float4*>(&Tb[e * TS + (i + 8) * 8 + 4]);
        th1 = b0.x*yf[0] + b0.y*yf[1] + b0.z*yf[2] + b0.w*yf[3]
            + b1.x*yf[4] + b1.y*yf[5] + b1.z*yf[6] + b1.w*yf[7];
    }
    x0S[e * XS + i]     = x0a + th0;
    x0S[e * XS + i + 8] = x0b + th1;

    // ---- out[b][i] = Cphi[i,:] @ u + CQH[i,:] @ w ----
    float oc = 0.f;
#pragma unroll
    for (int q = 0; q < 4; ++q) {
        const float4 A = *reinterpret_cast<const float4*>(&CpS[i * 20 + 4 * q]);
        const float4 U = *reinterpret_cast<const float4*>(&x0S[e * XS + 4 * q]);
        oc += A.x*U.x + A.y*U.y + A.z*U.z + A.w*U.w;
    }
    {
        const float4 q0 = *reinterpret_cast<const float4*>(&CQHS[i * 8 + 0]);
        const float4 q1 = *reinterpret_cast<const float4*>(&CQHS[i * 8 + 4]);
        oc += q0.x*yf[0] + q0.y*yf[1] + q0.z*yf[2] + q0.w*yf[3]
            + q1.x*yf[4] + q1.y*yf[5] + q1.z*yf[6] + q1.w*yf[7];
    }
    if (valid) out[b * 8 + i] = oc;
}

extern "C" void kernel_launch(void* const* d_in, const int* in_sizes, int n_in,
                              void* d_out, int out_size, void* d_ws, size_t ws_size,
                              hipStream_t stream)
{
    const float* z   = (const float*)d_in[0];
    const float* x0  = (const float*)d_in[1];
    const float* P0  = (const float*)d_in[2];
    const float* phi = (const float*)d_in[3];
    const float* H   = (const float*)d_in[4];
    const float* C   = (const float*)d_in[5];
    const float* Qd  = (const float*)d_in[6];
    const float* Rd  = (const float*)d_in[7];
    float* out = (float*)d_out;

    const int bs = in_sizes[0] / 8;          // z is [bs, 8]
    const int blocks = (bs + 31) / 32;       // 32 elements per block
    hipLaunchKernelGGL(kalman_fused10, dim3(blocks), dim3(256), 0, stream,
                       z, x0, P0, phi, H, C, Qd, Rd, out, bs);
}